// Round 1
// baseline (411.242 us; speedup 1.0000x reference)
//
#include <hip/hip_runtime.h>
#include <math.h>

#define B 4096
#define C 5
#define NNEG 20
#define D 128
#define NROWS (C + C * NNEG)  // 105 rows per batch element (5 pos + 100 neg)

// stable log sigmoid: logsig(x) = min(x,0) - log1p(exp(-|x|))
__device__ __forceinline__ float log_sigmoid(float x) {
    return fminf(x, 0.0f) - log1pf(__expf(-fabsf(x)));
}

// One block per batch element b. 256 threads = 4 waves.
// Wave w handles rows w, w+4, ... of the 105 (oword rows first, then nword rows).
// Lane l holds v1 dims [2l, 2l+1] as float2 -> each row read is one coalesced
// 512B wave transaction (8B/lane x 64 lanes).
__global__ __launch_bounds__(256) void sgns_partial(
    const int* __restrict__ iword,
    const int* __restrict__ owords,
    const int* __restrict__ nwords,
    const float* __restrict__ emb1,
    const float* __restrict__ emb2,
    float* __restrict__ partial)
{
    const int b    = blockIdx.x;
    const int tid  = threadIdx.x;
    const int lane = tid & 63;
    const int wave = tid >> 6;  // 0..3

    // center vector fragment (same for all 4 waves; L1 serves the repeats)
    const long center = (long)iword[b] * D;
    const float2 v1 = *(const float2*)(emb1 + center + 2 * lane);

    float acc = 0.0f;
    for (int r = wave; r < NROWS; r += 4) {
        const bool pos = (r < C);
        long idx;
        if (pos) idx = owords[b * C + r];
        else     idx = nwords[b * (C * NNEG) + (r - C)];

        const float2 row = *(const float2*)(emb2 + idx * D + 2 * lane);
        float s = v1.x * row.x + v1.y * row.y;

        // 64-lane butterfly reduction -> s uniform across the wave
        #pragma unroll
        for (int off = 32; off > 0; off >>= 1)
            s += __shfl_xor(s, off, 64);

        acc += log_sigmoid(pos ? s : -s);
    }

    __shared__ float wsum[4];
    if (lane == 0) wsum[wave] = acc;
    __syncthreads();
    if (tid == 0) partial[b] = wsum[0] + wsum[1] + wsum[2] + wsum[3];
}

// Single-block final reduction: out = -(sum of all logsig terms) / (B*C)
__global__ __launch_bounds__(256) void sgns_reduce(
    const float* __restrict__ partial,
    float* __restrict__ out)
{
    const int tid = threadIdx.x;
    float acc = 0.0f;
    for (int i = tid; i < B; i += 256) acc += partial[i];

    #pragma unroll
    for (int off = 32; off > 0; off >>= 1)
        acc += __shfl_xor(acc, off, 64);

    __shared__ float ws[4];
    if ((tid & 63) == 0) ws[tid >> 6] = acc;
    __syncthreads();
    if (tid == 0) out[0] = -(ws[0] + ws[1] + ws[2] + ws[3]) / (float)(B * C);
}

extern "C" void kernel_launch(void* const* d_in, const int* in_sizes, int n_in,
                              void* d_out, int out_size, void* d_ws, size_t ws_size,
                              hipStream_t stream) {
    const int*   iword  = (const int*)d_in[0];
    const int*   owords = (const int*)d_in[1];
    const int*   nwords = (const int*)d_in[2];
    const float* emb1   = (const float*)d_in[3];
    const float* emb2   = (const float*)d_in[4];
    float* out     = (float*)d_out;
    float* partial = (float*)d_ws;  // B floats = 16 KB

    sgns_partial<<<B, 256, 0, stream>>>(iword, owords, nwords, emb1, emb2, partial);
    sgns_reduce<<<1, 256, 0, stream>>>(partial, out);
}

// Round 2
// 357.378 us; speedup vs baseline: 1.1507x; 1.1507x over previous
//
#include <hip/hip_runtime.h>
#include <math.h>

#define B 4096
#define C 5
#define NNEG 20
#define D 128
#define NROWS (C + C * NNEG)  // 105 rows per batch element (5 pos + 100 neg)

// stable log sigmoid: logsig(x) = min(x,0) - log1p(exp(-|x|))
__device__ __forceinline__ float log_sigmoid(float x) {
    return fminf(x, 0.0f) - log1pf(__expf(-fabsf(x)));
}

// One block per batch element b. 256 threads = 4 waves = 32 row-groups.
// Each 8-lane group owns one row: lane j of a group reads float4s at dims
// 4j + 32k (k=0..3), so each load instruction is 128B-contiguous per group.
// 3-step intra-group butterfly reduces 8 rows per wave simultaneously;
// log_sigmoid computed once per 8 rows per wave (uniform within group).
__global__ __launch_bounds__(256) void sgns_partial(
    const int* __restrict__ iword,
    const int* __restrict__ owords,
    const int* __restrict__ nwords,
    const float* __restrict__ emb1,
    const float* __restrict__ emb2,
    float* __restrict__ partial)
{
    const int b    = blockIdx.x;
    const int tid  = threadIdx.x;
    const int lane = tid & 63;
    const int wave = tid >> 6;   // 0..3
    const int grp  = lane >> 3;  // 0..7  (row group within wave)
    const int j    = lane & 7;   // sublane: dim slice owner

    // v1 fragment: dims 4j+32k, k=0..3 (16 floats, registers)
    const long center = (long)iword[b] * D;
    const float4* v1p = (const float4*)(emb1 + center);
    float4 v1f[4];
    #pragma unroll
    for (int k = 0; k < 4; ++k) v1f[k] = v1p[j + 8 * k];

    float acc = 0.0f;  // each row's logsig will be counted 8x (once per group lane)

    #pragma unroll
    for (int pass = 0; pass < 4; ++pass) {
        const int r = pass * 32 + wave * 8 + grp;
        if (r < NROWS) {
            const bool pos = (r < C);
            long idx;
            if (pos) idx = owords[b * C + r];
            else     idx = nwords[b * (C * NNEG) + (r - C)];

            const float4* rp = (const float4*)(emb2 + idx * D);
            float s = 0.0f;
            #pragma unroll
            for (int k = 0; k < 4; ++k) {
                const float4 rw = rp[j + 8 * k];
                s += v1f[k].x * rw.x + v1f[k].y * rw.y
                   + v1f[k].z * rw.z + v1f[k].w * rw.w;
            }

            // 3-step butterfly within the 8-lane group (reduces 8 rows at once)
            s += __shfl_xor(s, 1, 64);
            s += __shfl_xor(s, 2, 64);
            s += __shfl_xor(s, 4, 64);

            acc += log_sigmoid(pos ? s : -s);
        }
    }

    // block reduction: every row counted 8x -> divide by 8 at the end
    #pragma unroll
    for (int off = 32; off > 0; off >>= 1)
        acc += __shfl_xor(acc, off, 64);

    __shared__ float wsum[4];
    if (lane == 0) wsum[wave] = acc;
    __syncthreads();
    if (tid == 0)
        partial[b] = (wsum[0] + wsum[1] + wsum[2] + wsum[3]) * 0.125f;
}

// Single-block final reduction: out = -(sum of all logsig terms) / (B*C)
__global__ __launch_bounds__(256) void sgns_reduce(
    const float* __restrict__ partial,
    float* __restrict__ out)
{
    const int tid = threadIdx.x;
    float acc = 0.0f;
    for (int i = tid; i < B; i += 256) acc += partial[i];

    #pragma unroll
    for (int off = 32; off > 0; off >>= 1)
        acc += __shfl_xor(acc, off, 64);

    __shared__ float ws[4];
    if ((tid & 63) == 0) ws[tid >> 6] = acc;
    __syncthreads();
    if (tid == 0) out[0] = -(ws[0] + ws[1] + ws[2] + ws[3]) / (float)(B * C);
}

extern "C" void kernel_launch(void* const* d_in, const int* in_sizes, int n_in,
                              void* d_out, int out_size, void* d_ws, size_t ws_size,
                              hipStream_t stream) {
    const int*   iword  = (const int*)d_in[0];
    const int*   owords = (const int*)d_in[1];
    const int*   nwords = (const int*)d_in[2];
    const float* emb1   = (const float*)d_in[3];
    const float* emb2   = (const float*)d_in[4];
    float* out     = (float*)d_out;
    float* partial = (float*)d_ws;  // B floats = 16 KB

    sgns_partial<<<B, 256, 0, stream>>>(iword, owords, nwords, emb1, emb2, partial);
    sgns_reduce<<<1, 256, 0, stream>>>(partial, out);
}

// Round 3
// 355.203 us; speedup vs baseline: 1.1578x; 1.0061x over previous
//
#include <hip/hip_runtime.h>
#include <math.h>

#define B 4096
#define C 5
#define NNEG 20
#define D 128
#define NROWS (C + C * NNEG)  // 105 rows per batch element (5 pos + 100 neg)

// stable log sigmoid: logsig(x) = min(x,0) - log1p(exp(-|x|))
__device__ __forceinline__ float log_sigmoid(float x) {
    return fminf(x, 0.0f) - log1pf(__expf(-fabsf(x)));
}

// One block per batch element b. 256 threads = 4 waves = 32 row-groups.
// Each 8-lane group owns row slots base, base+32, base+64, base+96.
// Structure: load 4 indices -> issue ALL 16 float4 row loads (prefetch,
// 16KB/wave outstanding) -> 4x {dot, 3-shuffle group butterfly, logsig}.
// Invalid tail slots (row >= 105) are clamped to index 0 (L1-hit dummy load)
// and masked out of the accumulation -> no divergent guards around loads.
__global__ __launch_bounds__(256) void sgns_partial(
    const int* __restrict__ iword,
    const int* __restrict__ owords,
    const int* __restrict__ nwords,
    const float* __restrict__ emb1,
    const float* __restrict__ emb2,
    float* __restrict__ partial)
{
    const int b    = blockIdx.x;
    const int tid  = threadIdx.x;
    const int lane = tid & 63;
    const int wave = tid >> 6;       // 0..3
    const int grp  = lane >> 3;      // 0..7
    const int j    = lane & 7;       // dim-slice owner within group
    const int base = wave * 8 + grp; // 0..31

    // v1 fragment: dims 4j+32k, k=0..3 (16 floats in registers)
    const long center = (long)iword[b] * D;
    const float4* v1p = (const float4*)(emb1 + center);
    float4 v1f[4];
    #pragma unroll
    for (int k = 0; k < 4; ++k) v1f[k] = v1p[j + 8 * k];

    // resolve the 4 row indices (clamp invalid tail slots to row-slot 0)
    int   rIdx[4];
    float sgn[4];
    bool  valid[4];
    #pragma unroll
    for (int p = 0; p < 4; ++p) {
        const int r = base + 32 * p;
        valid[p] = (r < NROWS);
        const int rr = valid[p] ? r : 0;
        const bool pos = (rr < C);
        sgn[p] = pos ? 1.0f : -1.0f;
        rIdx[p] = pos ? owords[b * C + rr]
                      : nwords[b * (C * NNEG) + (rr - C)];
    }

    // prefetch all 16 float4s (4 rows x 4 slices) before consuming any
    float4 rw[4][4];
    #pragma unroll
    for (int p = 0; p < 4; ++p) {
        const float4* rp = (const float4*)(emb2 + (long)rIdx[p] * D);
        #pragma unroll
        for (int k = 0; k < 4; ++k) rw[p][k] = rp[j + 8 * k];
    }

    float acc = 0.0f;
    #pragma unroll
    for (int p = 0; p < 4; ++p) {
        float s = 0.0f;
        #pragma unroll
        for (int k = 0; k < 4; ++k) {
            s += v1f[k].x * rw[p][k].x + v1f[k].y * rw[p][k].y
               + v1f[k].z * rw[p][k].z + v1f[k].w * rw[p][k].w;
        }
        // 3-step butterfly within the 8-lane group
        s += __shfl_xor(s, 1, 64);
        s += __shfl_xor(s, 2, 64);
        s += __shfl_xor(s, 4, 64);

        const float v = log_sigmoid(sgn[p] * s);
        acc += valid[p] ? v : 0.0f;
    }

    // acc is uniform within each 8-lane group -> reduce across groups only
    acc += __shfl_xor(acc, 8, 64);
    acc += __shfl_xor(acc, 16, 64);
    acc += __shfl_xor(acc, 32, 64);
    // every lane now holds the wave's total (each row counted exactly once)

    __shared__ float wsum[4];
    if (lane == 0) wsum[wave] = acc;
    __syncthreads();
    if (tid == 0)
        partial[b] = wsum[0] + wsum[1] + wsum[2] + wsum[3];
}

// Single-block final reduction: out = -(sum of all logsig terms) / (B*C)
__global__ __launch_bounds__(256) void sgns_reduce(
    const float* __restrict__ partial,
    float* __restrict__ out)
{
    const int tid = threadIdx.x;
    float acc = 0.0f;
    for (int i = tid; i < B; i += 256) acc += partial[i];

    #pragma unroll
    for (int off = 32; off > 0; off >>= 1)
        acc += __shfl_xor(acc, off, 64);

    __shared__ float ws[4];
    if ((tid & 63) == 0) ws[tid >> 6] = acc;
    __syncthreads();
    if (tid == 0) out[0] = -(ws[0] + ws[1] + ws[2] + ws[3]) / (float)(B * C);
}

extern "C" void kernel_launch(void* const* d_in, const int* in_sizes, int n_in,
                              void* d_out, int out_size, void* d_ws, size_t ws_size,
                              hipStream_t stream) {
    const int*   iword  = (const int*)d_in[0];
    const int*   owords = (const int*)d_in[1];
    const int*   nwords = (const int*)d_in[2];
    const float* emb1   = (const float*)d_in[3];
    const float* emb2   = (const float*)d_in[4];
    float* out     = (float*)d_out;
    float* partial = (float*)d_ws;  // B floats = 16 KB

    sgns_partial<<<B, 256, 0, stream>>>(iword, owords, nwords, emb1, emb2, partial);
    sgns_reduce<<<1, 256, 0, stream>>>(partial, out);
}